// Round 20
// baseline (149.153 us; speedup 1.0000x reference)
//
#include <hip/hip_runtime.h>
#include <hip/hip_bf16.h>

#define LSEQ 512
#define DDIM 300
#define HPAD 304

typedef __attribute__((ext_vector_type(8))) short short8;
typedef __attribute__((ext_vector_type(4))) float f32x4;

__device__ __forceinline__ void split4(f32x4 v, short8& hi, short8& lo, int base) {
  #pragma unroll
  for (int e = 0; e < 4; ++e) {
    const float f = v[e];
    const unsigned b = __float_as_uint(f);
    const float hf = __uint_as_float(b & 0xffff0000u);   // exact bf16-truncation
    hi[base + e] = (short)(b >> 16);
    lo[base + e] = (short)(__float_as_uint(f - hf) >> 16); // remainder, exact in f32
  }
}

// Fused kernel 1, INTERLEAVED block roles: every 4th block (bid%4==3,
// bid<4864) is an h-block, so each CU holds ~3 ew + 1 h concurrently and the
// h compute hides under the ew stream's HBM stalls (vs R12/R16 where h ran
// as a serial batch).  Work mapping is a pure permutation of R19's.
__global__ __launch_bounds__(256, 3) void k_fused1(
    const float* __restrict__ emb, const int* __restrict__ adj,
    const float* __restrict__ Wmap, const float* __restrict__ wew,
    const float* __restrict__ x, const float* __restrict__ Weto,
    const float* __restrict__ beto,
    float* __restrict__ att, float* __restrict__ h) {
  __shared__ float stg[2][4][1024];   // 32 KB staging (ew path only)
  __shared__ float ew_lds[LSEQ];
  __shared__ float redA[4], redB[4], redC[4];
  const int tid = threadIdx.x;
  const int lane = tid & 63, wid = tid >> 6;
  const int c = lane & 15, g = lane >> 4;

  // block-role mapping: bid<4864: r==3 -> h (idx q), else ew (idx 3q+r);
  // bid>=4864 -> ew (idx 3648 + bid-4864).  ew 0..4095, h 0..1215.
  const int bid = blockIdx.x;
  const int q = bid >> 2, r = bid & 3;
  const bool is_h = (bid < 4864) && (r == 3);
  const int idx = (bid < 4864) ? (is_h ? q : 3 * q + r) : (3648 + bid - 4864);

  if (is_h) {
    // ---------------- h path ----------------
    const int gt = idx * 4 + wid;                   // 0..4863
    const int rt = gt / 19, dt = gt % 19;
    const int r0 = rt * 16, d0 = dt * 16;
    const int dc = min(d0 + c, DDIM - 1);
    const float* xr = x + (size_t)(r0 + c) * DDIM;

    f32x4 acc = {0.f, 0.f, 0.f, 0.f};
    #pragma unroll 3
    for (int ks = 0; ks < 9; ++ks) {
      const int k0 = ks * 32 + 8 * g;
      const f32x4 a0 = *(const f32x4*)(xr + k0);
      const f32x4 a1 = *(const f32x4*)(xr + k0 + 4);
      short8 ahi, alo;
      split4(a0, ahi, alo, 0);
      split4(a1, ahi, alo, 4);
      const float* wp = Weto + (size_t)k0 * DDIM + dc;
      const f32x4 b0 = {wp[0], wp[DDIM], wp[2 * DDIM], wp[3 * DDIM]};
      const f32x4 b1 = {wp[4 * DDIM], wp[5 * DDIM], wp[6 * DDIM], wp[7 * DDIM]};
      short8 bhi, blo;
      split4(b0, bhi, blo, 0);
      split4(b1, bhi, blo, 4);
      acc = __builtin_amdgcn_mfma_f32_16x16x32_bf16(ahi, bhi, acc, 0, 0, 0);
      acc = __builtin_amdgcn_mfma_f32_16x16x32_bf16(ahi, blo, acc, 0, 0, 0);
      acc = __builtin_amdgcn_mfma_f32_16x16x32_bf16(alo, bhi, acc, 0, 0, 0);
    }
    {   // K-tail 288..299 masked
      float av[8], bv[8];
      #pragma unroll
      for (int e = 0; e < 8; ++e) {
        const int kk = 288 + 8 * g + e;
        const bool ok = kk < DDIM;
        av[e] = ok ? xr[kk] : 0.f;
        bv[e] = ok ? Weto[(size_t)kk * DDIM + dc] : 0.f;
      }
      const f32x4 a0 = {av[0], av[1], av[2], av[3]};
      const f32x4 a1 = {av[4], av[5], av[6], av[7]};
      const f32x4 b0 = {bv[0], bv[1], bv[2], bv[3]};
      const f32x4 b1 = {bv[4], bv[5], bv[6], bv[7]};
      short8 ahi, alo, bhi, blo;
      split4(a0, ahi, alo, 0);
      split4(a1, ahi, alo, 4);
      split4(b0, bhi, blo, 0);
      split4(b1, bhi, blo, 4);
      acc = __builtin_amdgcn_mfma_f32_16x16x32_bf16(ahi, bhi, acc, 0, 0, 0);
      acc = __builtin_amdgcn_mfma_f32_16x16x32_bf16(ahi, blo, acc, 0, 0, 0);
      acc = __builtin_amdgcn_mfma_f32_16x16x32_bf16(alo, bhi, acc, 0, 0, 0);
    }
    if (d0 + c < DDIM) {
      const float bb = beto[d0 + c];
      #pragma unroll
      for (int reg = 0; reg < 4; ++reg)
        h[(size_t)(r0 + 4 * g + reg) * HPAD + d0 + c] = acc[reg] + bb;
    }
    return;
  }

  // ---------------- ew + softmax path (one (b,i) row per block) ----------------
  short8 whi[4][2], wlo[4][2];
  #pragma unroll
  for (int nt = 0; nt < 4; ++nt) {
    #pragma unroll
    for (int s = 0; s < 2; ++s) {
      #pragma unroll
      for (int e2 = 0; e2 < 2; ++e2) {
        f32x4 w;
        #pragma unroll
        for (int e = 0; e < 4; ++e)
          w[e] = Wmap[(32 * s + 8 * g + 4 * e2 + e) * 64 + 16 * nt + c];
        split4(w, whi[nt][s], wlo[nt][s], 4 * e2);
      }
    }
  }
  float wv2[4][4];
  #pragma unroll
  for (int nt = 0; nt < 4; ++nt)
    #pragma unroll
    for (int reg = 0; reg < 4; ++reg)
      wv2[nt][reg] = wew[16 * nt + 4 * g + reg];

  const size_t rowbase = (size_t)idx * LSEQ;
  const size_t ebase = rowbase + (size_t)wid * 128;
  const float* gbase = emb + (ebase << 6);

  float* const lb0 = &stg[0][wid][0];
  float* const lb1 = &stg[1][wid][0];

  int wwb[4];
  #pragma unroll
  for (int i = 0; i < 4; ++i)
    wwb[i] = ((i * 1024 + lane * 16) ^ ((((i & 1) * 4 + g) & 7) << 4)) >> 2;

  const int rw0 = (c * 256 + (((2 * g + 0) ^ (c & 7)) << 4)) >> 2;
  const int rw1 = (c * 256 + (((2 * g + 1) ^ (c & 7)) << 4)) >> 2;
  const int rw2 = (c * 256 + (((2 * g + 8) ^ (c & 7)) << 4)) >> 2;
  const int rw3 = (c * 256 + (((2 * g + 9) ^ (c & 7)) << 4)) >> 2;

  f32x4 q0 = *(const f32x4*)(gbase + 0 * 256 + lane * 4);
  f32x4 q1 = *(const f32x4*)(gbase + 1 * 256 + lane * 4);
  f32x4 q2 = *(const f32x4*)(gbase + 2 * 256 + lane * 4);
  f32x4 q3 = *(const f32x4*)(gbase + 3 * 256 + lane * 4);
  *(f32x4*)(lb0 + wwb[0]) = q0;
  *(f32x4*)(lb0 + wwb[1]) = q1;
  *(f32x4*)(lb0 + wwb[2]) = q2;
  *(f32x4*)(lb0 + wwb[3]) = q3;

  #pragma unroll 1
  for (int it = 0; it < 8; ++it) {
    if (it < 7) {
      const float* nt_ = gbase + (size_t)(it + 1) * 1024;
      q0 = *(const f32x4*)(nt_ + 0 * 256 + lane * 4);
      q1 = *(const f32x4*)(nt_ + 1 * 256 + lane * 4);
      q2 = *(const f32x4*)(nt_ + 2 * 256 + lane * 4);
      q3 = *(const f32x4*)(nt_ + 3 * 256 + lane * 4);
    }
    float* const rb = (it & 1) ? lb1 : lb0;
    const f32x4 a0 = *(const f32x4*)(rb + rw0);
    const f32x4 a1 = *(const f32x4*)(rb + rw1);
    const f32x4 a2 = *(const f32x4*)(rb + rw2);
    const f32x4 a3 = *(const f32x4*)(rb + rw3);

    short8 ehi[2], elo[2];
    split4(a0, ehi[0], elo[0], 0);
    split4(a1, ehi[0], elo[0], 4);
    split4(a2, ehi[1], elo[1], 0);
    split4(a3, ehi[1], elo[1], 4);

    f32x4 acc[4];
    #pragma unroll
    for (int nt = 0; nt < 4; ++nt) acc[nt] = (f32x4){0.f, 0.f, 0.f, 0.f};
    #pragma unroll
    for (int s = 0; s < 2; ++s) {
      #pragma unroll
      for (int nt = 0; nt < 4; ++nt) {
        acc[nt] = __builtin_amdgcn_mfma_f32_16x16x32_bf16(whi[nt][s], ehi[s], acc[nt], 0, 0, 0);
        acc[nt] = __builtin_amdgcn_mfma_f32_16x16x32_bf16(whi[nt][s], elo[s], acc[nt], 0, 0, 0);
        acc[nt] = __builtin_amdgcn_mfma_f32_16x16x32_bf16(wlo[nt][s], ehi[s], acc[nt], 0, 0, 0);
      }
    }
    float p = 0.f;
    #pragma unroll
    for (int nt = 0; nt < 4; ++nt)
      #pragma unroll
      for (int reg = 0; reg < 4; ++reg)
        p = fmaf(fmaxf(acc[nt][reg], 0.f), wv2[nt][reg], p);
    p += __shfl_xor(p, 16, 64);
    p += __shfl_xor(p, 32, 64);
    if (lane < 16) ew_lds[wid * 128 + it * 16 + c] = p;

    if (it < 7) {
      float* const wb = (it & 1) ? lb0 : lb1;
      *(f32x4*)(wb + wwb[0]) = q0;
      *(f32x4*)(wb + wwb[1]) = q1;
      *(f32x4*)(wb + wwb[2]) = q2;
      *(f32x4*)(wb + wwb[3]) = q3;
    }
  }
  __syncthreads();

  // row-mean normalize + masked softmax (verified tail)
  const float ew0 = ew_lds[tid];
  const float ew1 = ew_lds[tid + 256];

  float ls = ew0 + ew1;
  #pragma unroll
  for (int m = 32; m >= 1; m >>= 1) ls += __shfl_xor(ls, m, 64);
  if (lane == 0) redA[wid] = ls;
  __syncthreads();
  const float rmean =
      fabsf((redA[0] + redA[1] + redA[2] + redA[3]) * (1.0f / 512.0f)) + 1e-10f;

  const int a0i = adj[rowbase + tid];
  const int a1i = adj[rowbase + tid + 256];
  const float sc0 = a0i ? (ew0 / rmean) : -9e15f;
  const float sc1 = a1i ? (ew1 / rmean) : -9e15f;

  float lm = fmaxf(sc0, sc1);
  #pragma unroll
  for (int m = 32; m >= 1; m >>= 1) lm = fmaxf(lm, __shfl_xor(lm, m, 64));
  if (lane == 0) redB[wid] = lm;
  __syncthreads();
  const float mx = fmaxf(fmaxf(redB[0], redB[1]), fmaxf(redB[2], redB[3]));

  const float e0 = expf(sc0 - mx);
  const float e1 = expf(sc1 - mx);
  float es = e0 + e1;
  #pragma unroll
  for (int m = 32; m >= 1; m >>= 1) es += __shfl_xor(es, m, 64);
  if (lane == 0) redC[wid] = es;
  __syncthreads();
  const float denom = redC[0] + redC[1] + redC[2] + redC[3];

  att[rowbase + tid] = e0 / denom;
  att[rowbase + tid + 256] = e1 / denom;
}

// h_edge = relu(att @ h) — R19 v3 (measured ~24.5 us, best k_out variant).
__global__ __launch_bounds__(256) void k_out(
    const float* __restrict__ att, const float* __restrict__ h,
    float* __restrict__ out) {
  __shared__ float lds_h[2][32 * 160];    // 2 x 20 KB
  const int tid = threadIdx.x;
  const int lane = tid & 63, wid = tid >> 6;
  const int c = lane & 15, g = lane >> 4;
  const int b = blockIdx.x & 7;           // XCD-pinned batch
  const int t = blockIdx.x >> 3;          // 0..63
  const int i0 = (t & 31) * 16;
  const int dhalf = t >> 5;               // 0 or 1
  const float* hB = h + (size_t)b * LSEQ * HPAD + dhalf * 160;
  const float* attR = att + ((size_t)b * LSEQ + i0 + c) * LSEQ + 8 * g;

  f32x4 acc[3];
  #pragma unroll
  for (int j = 0; j < 3; ++j) acc[j] = (f32x4){0.f, 0.f, 0.f, 0.f};

  // prologue: stage K-step 0 (1280 vec4, coalesced)
  #pragma unroll
  for (int j = 0; j < 5; ++j) {
    const int v = tid + 256 * j;
    const int row = v / 40, c4 = v % 40;
    *(f32x4*)(&lds_h[0][row * 160 + c4 * 4]) =
        *(const f32x4*)(hB + (size_t)row * HPAD + c4 * 4);
  }
  __syncthreads();

  #pragma unroll 1
  for (int ks = 0; ks < 16; ++ks) {
    const float* cur = lds_h[ks & 1];
    if (ks < 15) {   // stage next K-step into the other buffer
      float* nxt = lds_h[(ks + 1) & 1];
      const float* src = hB + (size_t)(ks + 1) * 32 * HPAD;
      #pragma unroll
      for (int j = 0; j < 5; ++j) {
        const int v = tid + 256 * j;
        const int row = v / 40, c4 = v % 40;
        *(f32x4*)(&nxt[row * 160 + c4 * 4]) =
            *(const f32x4*)(src + (size_t)row * HPAD + c4 * 4);
      }
    }
    const f32x4 a0 = *(const f32x4*)(attR + ks * 32);
    const f32x4 a1 = *(const f32x4*)(attR + ks * 32 + 4);
    short8 ahi, alo;
    split4(a0, ahi, alo, 0);
    split4(a1, ahi, alo, 4);
    #pragma unroll
    for (int j = 0; j < 3; ++j) {
      const int dtl = wid + 4 * j;
      const int dt = dhalf * 10 + dtl;
      if (dtl < 10 && dt < 19) {
        const int colb = dtl * 16 + c;
        f32x4 b0, b1;
        #pragma unroll
        for (int e = 0; e < 4; ++e) {
          b0[e] = cur[(8 * g + e) * 160 + colb];
          b1[e] = cur[(8 * g + 4 + e) * 160 + colb];
        }
        short8 bhi, blo;
        split4(b0, bhi, blo, 0);
        split4(b1, bhi, blo, 4);
        acc[j] = __builtin_amdgcn_mfma_f32_16x16x32_bf16(ahi, bhi, acc[j], 0, 0, 0);
        acc[j] = __builtin_amdgcn_mfma_f32_16x16x32_bf16(ahi, blo, acc[j], 0, 0, 0);
        acc[j] = __builtin_amdgcn_mfma_f32_16x16x32_bf16(alo, bhi, acc[j], 0, 0, 0);
      }
    }
    __syncthreads();
  }

  #pragma unroll
  for (int j = 0; j < 3; ++j) {
    const int dtl = wid + 4 * j;
    const int dt = dhalf * 10 + dtl;
    if (dtl < 10 && dt < 19) {
      const int d = dt * 16 + c;
      if (d < DDIM) {
        #pragma unroll
        for (int reg = 0; reg < 4; ++reg)
          out[((size_t)b * LSEQ + i0 + 4 * g + reg) * DDIM + d] =
              fmaxf(acc[j][reg], 0.f);
      }
    }
  }
}

extern "C" void kernel_launch(void* const* d_in, const int* in_sizes, int n_in,
                              void* d_out, int out_size, void* d_ws, size_t ws_size,
                              hipStream_t stream) {
  const float* x    = (const float*)d_in[0];   // [8,512,300]
  const int*   adj  = (const int*)d_in[1];     // [8,512,512]
  const float* emb  = (const float*)d_in[2];   // [8,512,512,64]
  const float* Wmap = (const float*)d_in[3];   // [64,64]
  const float* wew  = (const float*)d_in[4];   // [64,1]
  const float* Weto = (const float*)d_in[5];   // [300,300]
  const float* beto = (const float*)d_in[6];   // [300]

  float* out    = (float*)d_out;
  float* h_edge = out;                               // [8,512,300]
  float* att    = out + (size_t)8 * LSEQ * DDIM;     // [8,512,512]
  float* h      = (float*)d_ws;                      // [8,512,304] scratch

  // fused: ew+softmax ∥ h, INTERLEAVED 3:1 so h compute hides in ew's
  // HBM stalls on every CU (vs batch-ordered R12/R16)
  k_fused1<<<dim3(4096 + 1216), 256, 0, stream>>>(emb, adj, Wmap, wew, x, Weto,
                                                  beto, att, h);
  // h_edge = relu(att @ h)
  k_out<<<dim3(512), 256, 0, stream>>>(att, h, h_edge);
}

// Round 21
// 144.519 us; speedup vs baseline: 1.0321x; 1.0321x over previous
//
#include <hip/hip_runtime.h>
#include <hip/hip_bf16.h>

#define LSEQ 512
#define DDIM 300
#define HPAD 304

typedef __attribute__((ext_vector_type(8))) short short8;
typedef __attribute__((ext_vector_type(4))) float f32x4;

__device__ __forceinline__ void split4(f32x4 v, short8& hi, short8& lo, int base) {
  #pragma unroll
  for (int e = 0; e < 4; ++e) {
    const float f = v[e];
    const unsigned b = __float_as_uint(f);
    const float hf = __uint_as_float(b & 0xffff0000u);   // exact bf16-truncation
    hi[base + e] = (short)(b >> 16);
    lo[base + e] = (short)(__float_as_uint(f - hf) >> 16); // remainder, exact in f32
  }
}

// Fused kernel 1 (R12/R19 config, h stored pitch-304) — best measured:
//  blocks 0..4095   : ew row -> in-LDS softmax -> att row.
//  blocks 4096..5311: h = x@W_eto + b (16x16 wave-tile split-bf16 MFMA).
__global__ __launch_bounds__(256, 3) void k_fused1(
    const float* __restrict__ emb, const int* __restrict__ adj,
    const float* __restrict__ Wmap, const float* __restrict__ wew,
    const float* __restrict__ x, const float* __restrict__ Weto,
    const float* __restrict__ beto,
    float* __restrict__ att, float* __restrict__ h) {
  __shared__ float stg[2][4][1024];   // 32 KB staging (ew path only)
  __shared__ float ew_lds[LSEQ];
  __shared__ float redA[4], redB[4], redC[4];
  const int tid = threadIdx.x;
  const int lane = tid & 63, wid = tid >> 6;
  const int c = lane & 15, g = lane >> 4;

  if (blockIdx.x >= 4096) {
    // ---------------- h path ----------------
    const int gt = (blockIdx.x - 4096) * 4 + wid;   // 0..4863
    const int rt = gt / 19, dt = gt % 19;
    const int r0 = rt * 16, d0 = dt * 16;
    const int dc = min(d0 + c, DDIM - 1);
    const float* xr = x + (size_t)(r0 + c) * DDIM;

    f32x4 acc = {0.f, 0.f, 0.f, 0.f};
    #pragma unroll 3
    for (int ks = 0; ks < 9; ++ks) {
      const int k0 = ks * 32 + 8 * g;
      const f32x4 a0 = *(const f32x4*)(xr + k0);
      const f32x4 a1 = *(const f32x4*)(xr + k0 + 4);
      short8 ahi, alo;
      split4(a0, ahi, alo, 0);
      split4(a1, ahi, alo, 4);
      const float* wp = Weto + (size_t)k0 * DDIM + dc;
      const f32x4 b0 = {wp[0], wp[DDIM], wp[2 * DDIM], wp[3 * DDIM]};
      const f32x4 b1 = {wp[4 * DDIM], wp[5 * DDIM], wp[6 * DDIM], wp[7 * DDIM]};
      short8 bhi, blo;
      split4(b0, bhi, blo, 0);
      split4(b1, bhi, blo, 4);
      acc = __builtin_amdgcn_mfma_f32_16x16x32_bf16(ahi, bhi, acc, 0, 0, 0);
      acc = __builtin_amdgcn_mfma_f32_16x16x32_bf16(ahi, blo, acc, 0, 0, 0);
      acc = __builtin_amdgcn_mfma_f32_16x16x32_bf16(alo, bhi, acc, 0, 0, 0);
    }
    {   // K-tail 288..299 masked
      float av[8], bv[8];
      #pragma unroll
      for (int e = 0; e < 8; ++e) {
        const int kk = 288 + 8 * g + e;
        const bool ok = kk < DDIM;
        av[e] = ok ? xr[kk] : 0.f;
        bv[e] = ok ? Weto[(size_t)kk * DDIM + dc] : 0.f;
      }
      const f32x4 a0 = {av[0], av[1], av[2], av[3]};
      const f32x4 a1 = {av[4], av[5], av[6], av[7]};
      const f32x4 b0 = {bv[0], bv[1], bv[2], bv[3]};
      const f32x4 b1 = {bv[4], bv[5], bv[6], bv[7]};
      short8 ahi, alo, bhi, blo;
      split4(a0, ahi, alo, 0);
      split4(a1, ahi, alo, 4);
      split4(b0, bhi, blo, 0);
      split4(b1, bhi, blo, 4);
      acc = __builtin_amdgcn_mfma_f32_16x16x32_bf16(ahi, bhi, acc, 0, 0, 0);
      acc = __builtin_amdgcn_mfma_f32_16x16x32_bf16(ahi, blo, acc, 0, 0, 0);
      acc = __builtin_amdgcn_mfma_f32_16x16x32_bf16(alo, bhi, acc, 0, 0, 0);
    }
    if (d0 + c < DDIM) {
      const float bb = beto[d0 + c];
      #pragma unroll
      for (int reg = 0; reg < 4; ++reg)
        h[(size_t)(r0 + 4 * g + reg) * HPAD + d0 + c] = acc[reg] + bb;
    }
    return;
  }

  // ---------------- ew + softmax path (one (b,i) row per block) ----------------
  short8 whi[4][2], wlo[4][2];
  #pragma unroll
  for (int nt = 0; nt < 4; ++nt) {
    #pragma unroll
    for (int s = 0; s < 2; ++s) {
      #pragma unroll
      for (int e2 = 0; e2 < 2; ++e2) {
        f32x4 w;
        #pragma unroll
        for (int e = 0; e < 4; ++e)
          w[e] = Wmap[(32 * s + 8 * g + 4 * e2 + e) * 64 + 16 * nt + c];
        split4(w, whi[nt][s], wlo[nt][s], 4 * e2);
      }
    }
  }
  float wv2[4][4];
  #pragma unroll
  for (int nt = 0; nt < 4; ++nt)
    #pragma unroll
    for (int reg = 0; reg < 4; ++reg)
      wv2[nt][reg] = wew[16 * nt + 4 * g + reg];

  const size_t rowbase = (size_t)blockIdx.x * LSEQ;
  const size_t ebase = rowbase + (size_t)wid * 128;
  const float* gbase = emb + (ebase << 6);

  float* const lb0 = &stg[0][wid][0];
  float* const lb1 = &stg[1][wid][0];

  int wwb[4];
  #pragma unroll
  for (int i = 0; i < 4; ++i)
    wwb[i] = ((i * 1024 + lane * 16) ^ ((((i & 1) * 4 + g) & 7) << 4)) >> 2;

  const int rw0 = (c * 256 + (((2 * g + 0) ^ (c & 7)) << 4)) >> 2;
  const int rw1 = (c * 256 + (((2 * g + 1) ^ (c & 7)) << 4)) >> 2;
  const int rw2 = (c * 256 + (((2 * g + 8) ^ (c & 7)) << 4)) >> 2;
  const int rw3 = (c * 256 + (((2 * g + 9) ^ (c & 7)) << 4)) >> 2;

  f32x4 q0 = *(const f32x4*)(gbase + 0 * 256 + lane * 4);
  f32x4 q1 = *(const f32x4*)(gbase + 1 * 256 + lane * 4);
  f32x4 q2 = *(const f32x4*)(gbase + 2 * 256 + lane * 4);
  f32x4 q3 = *(const f32x4*)(gbase + 3 * 256 + lane * 4);
  *(f32x4*)(lb0 + wwb[0]) = q0;
  *(f32x4*)(lb0 + wwb[1]) = q1;
  *(f32x4*)(lb0 + wwb[2]) = q2;
  *(f32x4*)(lb0 + wwb[3]) = q3;

  #pragma unroll 1
  for (int it = 0; it < 8; ++it) {
    if (it < 7) {
      const float* nt_ = gbase + (size_t)(it + 1) * 1024;
      q0 = *(const f32x4*)(nt_ + 0 * 256 + lane * 4);
      q1 = *(const f32x4*)(nt_ + 1 * 256 + lane * 4);
      q2 = *(const f32x4*)(nt_ + 2 * 256 + lane * 4);
      q3 = *(const f32x4*)(nt_ + 3 * 256 + lane * 4);
    }
    float* const rb = (it & 1) ? lb1 : lb0;
    const f32x4 a0 = *(const f32x4*)(rb + rw0);
    const f32x4 a1 = *(const f32x4*)(rb + rw1);
    const f32x4 a2 = *(const f32x4*)(rb + rw2);
    const f32x4 a3 = *(const f32x4*)(rb + rw3);

    short8 ehi[2], elo[2];
    split4(a0, ehi[0], elo[0], 0);
    split4(a1, ehi[0], elo[0], 4);
    split4(a2, ehi[1], elo[1], 0);
    split4(a3, ehi[1], elo[1], 4);

    f32x4 acc[4];
    #pragma unroll
    for (int nt = 0; nt < 4; ++nt) acc[nt] = (f32x4){0.f, 0.f, 0.f, 0.f};
    #pragma unroll
    for (int s = 0; s < 2; ++s) {
      #pragma unroll
      for (int nt = 0; nt < 4; ++nt) {
        acc[nt] = __builtin_amdgcn_mfma_f32_16x16x32_bf16(whi[nt][s], ehi[s], acc[nt], 0, 0, 0);
        acc[nt] = __builtin_amdgcn_mfma_f32_16x16x32_bf16(whi[nt][s], elo[s], acc[nt], 0, 0, 0);
        acc[nt] = __builtin_amdgcn_mfma_f32_16x16x32_bf16(wlo[nt][s], ehi[s], acc[nt], 0, 0, 0);
      }
    }
    float p = 0.f;
    #pragma unroll
    for (int nt = 0; nt < 4; ++nt)
      #pragma unroll
      for (int reg = 0; reg < 4; ++reg)
        p = fmaf(fmaxf(acc[nt][reg], 0.f), wv2[nt][reg], p);
    p += __shfl_xor(p, 16, 64);
    p += __shfl_xor(p, 32, 64);
    if (lane < 16) ew_lds[wid * 128 + it * 16 + c] = p;

    if (it < 7) {
      float* const wb = (it & 1) ? lb0 : lb1;
      *(f32x4*)(wb + wwb[0]) = q0;
      *(f32x4*)(wb + wwb[1]) = q1;
      *(f32x4*)(wb + wwb[2]) = q2;
      *(f32x4*)(wb + wwb[3]) = q3;
    }
  }
  __syncthreads();

  // row-mean normalize + masked softmax (verified tail)
  const float ew0 = ew_lds[tid];
  const float ew1 = ew_lds[tid + 256];

  float ls = ew0 + ew1;
  #pragma unroll
  for (int m = 32; m >= 1; m >>= 1) ls += __shfl_xor(ls, m, 64);
  if (lane == 0) redA[wid] = ls;
  __syncthreads();
  const float rmean =
      fabsf((redA[0] + redA[1] + redA[2] + redA[3]) * (1.0f / 512.0f)) + 1e-10f;

  const int a0i = adj[rowbase + tid];
  const int a1i = adj[rowbase + tid + 256];
  const float sc0 = a0i ? (ew0 / rmean) : -9e15f;
  const float sc1 = a1i ? (ew1 / rmean) : -9e15f;

  float lm = fmaxf(sc0, sc1);
  #pragma unroll
  for (int m = 32; m >= 1; m >>= 1) lm = fmaxf(lm, __shfl_xor(lm, m, 64));
  if (lane == 0) redB[wid] = lm;
  __syncthreads();
  const float mx = fmaxf(fmaxf(redB[0], redB[1]), fmaxf(redB[2], redB[3]));

  const float e0 = expf(sc0 - mx);
  const float e1 = expf(sc1 - mx);
  float es = e0 + e1;
  #pragma unroll
  for (int m = 32; m >= 1; m >>= 1) es += __shfl_xor(es, m, 64);
  if (lane == 0) redC[wid] = es;
  __syncthreads();
  const float denom = redC[0] + redC[1] + redC[2] + redC[3];

  att[rowbase + tid] = e0 / denom;
  att[rowbase + tid + 256] = e1 / denom;
}

// h_edge = relu(att @ h) — R19 v3 (best k_out variant, ~24.5 us): one block
// per (b, 16-row i-tile, d-half), 512 blocks (2/CU), 2x20KB LDS h-slab,
// att rows loaded once per block, b = blockIdx&7 pins batch->XCD.
__global__ __launch_bounds__(256) void k_out(
    const float* __restrict__ att, const float* __restrict__ h,
    float* __restrict__ out) {
  __shared__ float lds_h[2][32 * 160];    // 2 x 20 KB
  const int tid = threadIdx.x;
  const int lane = tid & 63, wid = tid >> 6;
  const int c = lane & 15, g = lane >> 4;
  const int b = blockIdx.x & 7;           // XCD-pinned batch
  const int t = blockIdx.x >> 3;          // 0..63
  const int i0 = (t & 31) * 16;
  const int dhalf = t >> 5;               // 0 or 1
  const float* hB = h + (size_t)b * LSEQ * HPAD + dhalf * 160;
  const float* attR = att + ((size_t)b * LSEQ + i0 + c) * LSEQ + 8 * g;

  f32x4 acc[3];
  #pragma unroll
  for (int j = 0; j < 3; ++j) acc[j] = (f32x4){0.f, 0.f, 0.f, 0.f};

  // prologue: stage K-step 0 (1280 vec4, coalesced)
  #pragma unroll
  for (int j = 0; j < 5; ++j) {
    const int v = tid + 256 * j;
    const int row = v / 40, c4 = v % 40;
    *(f32x4*)(&lds_h[0][row * 160 + c4 * 4]) =
        *(const f32x4*)(hB + (size_t)row * HPAD + c4 * 4);
  }
  __syncthreads();

  #pragma unroll 1
  for (int ks = 0; ks < 16; ++ks) {
    const float* cur = lds_h[ks & 1];
    if (ks < 15) {   // stage next K-step into the other buffer
      float* nxt = lds_h[(ks + 1) & 1];
      const float* src = hB + (size_t)(ks + 1) * 32 * HPAD;
      #pragma unroll
      for (int j = 0; j < 5; ++j) {
        const int v = tid + 256 * j;
        const int row = v / 40, c4 = v % 40;
        *(f32x4*)(&nxt[row * 160 + c4 * 4]) =
            *(const f32x4*)(src + (size_t)row * HPAD + c4 * 4);
      }
    }
    const f32x4 a0 = *(const f32x4*)(attR + ks * 32);
    const f32x4 a1 = *(const f32x4*)(attR + ks * 32 + 4);
    short8 ahi, alo;
    split4(a0, ahi, alo, 0);
    split4(a1, ahi, alo, 4);
    #pragma unroll
    for (int j = 0; j < 3; ++j) {
      const int dtl = wid + 4 * j;
      const int dt = dhalf * 10 + dtl;
      if (dtl < 10 && dt < 19) {
        const int colb = dtl * 16 + c;
        f32x4 b0, b1;
        #pragma unroll
        for (int e = 0; e < 4; ++e) {
          b0[e] = cur[(8 * g + e) * 160 + colb];
          b1[e] = cur[(8 * g + 4 + e) * 160 + colb];
        }
        short8 bhi, blo;
        split4(b0, bhi, blo, 0);
        split4(b1, bhi, blo, 4);
        acc[j] = __builtin_amdgcn_mfma_f32_16x16x32_bf16(ahi, bhi, acc[j], 0, 0, 0);
        acc[j] = __builtin_amdgcn_mfma_f32_16x16x32_bf16(ahi, blo, acc[j], 0, 0, 0);
        acc[j] = __builtin_amdgcn_mfma_f32_16x16x32_bf16(alo, bhi, acc[j], 0, 0, 0);
      }
    }
    __syncthreads();
  }

  #pragma unroll
  for (int j = 0; j < 3; ++j) {
    const int dtl = wid + 4 * j;
    const int dt = dhalf * 10 + dtl;
    if (dtl < 10 && dt < 19) {
      const int d = dt * 16 + c;
      if (d < DDIM) {
        #pragma unroll
        for (int reg = 0; reg < 4; ++reg)
          out[((size_t)b * LSEQ + i0 + 4 * g + reg) * DDIM + d] =
              fmaxf(acc[j][reg], 0.f);
      }
    }
  }
}

extern "C" void kernel_launch(void* const* d_in, const int* in_sizes, int n_in,
                              void* d_out, int out_size, void* d_ws, size_t ws_size,
                              hipStream_t stream) {
  const float* x    = (const float*)d_in[0];   // [8,512,300]
  const int*   adj  = (const int*)d_in[1];     // [8,512,512]
  const float* emb  = (const float*)d_in[2];   // [8,512,512,64]
  const float* Wmap = (const float*)d_in[3];   // [64,64]
  const float* wew  = (const float*)d_in[4];   // [64,1]
  const float* Weto = (const float*)d_in[5];   // [300,300]
  const float* beto = (const float*)d_in[6];   // [300]

  float* out    = (float*)d_out;
  float* h_edge = out;                               // [8,512,300]
  float* att    = out + (size_t)8 * LSEQ * DDIM;     // [8,512,512]
  float* h      = (float*)d_ws;                      // [8,512,304] scratch

  // fused: ew+softmax (blocks 0..4095) ∥ h pitch-304 (blocks 4096..5311)
  k_fused1<<<dim3(4096 + 1216), 256, 0, stream>>>(emb, adj, Wmap, wew, x, Weto,
                                                  beto, att, h);
  // h_edge = relu(att @ h)
  k_out<<<dim3(512), 256, 0, stream>>>(att, h, h_edge);
}